// Round 3
// baseline (44661.520 us; speedup 1.0000x reference)
//
#include <hip/hip_runtime.h>
#include <stdint.h>

// Problem constants
#define BB   64
#define TT   250
#define INN  1024
#define HIDD 2048
#define OUTT 256

#define DECAYF 0.951229424500714f   // exp(-1/20)
#define ALPHAF 0.951229424500714f
#define LRF    1e-4f
#define WDF    0.01f
#define SCLF   0.2f

#define NBLK 280u

// d_out offsets (float elements), concatenated return order:
// l1_seq [64,250,2048], l2_seq [64,250,256], v1 [64,2048], v2 [64,256],
// l1_tr [64,2048], l2_tr [64,256]
#define O_L1SEQ 0
#define O_L2SEQ 32768000
#define O_V1    36864000
#define O_V2    36995072
#define O_L1TR  37011456
#define O_L2TR  37142528

// workspace layout (byte offsets), ~7 MB total
#define WS_PC1   0         // f32 [8][64][2048]  gemm1 split-K partials
#define WS_PC2   4194304   // f32 [16][64][256]  gemm2 split-K partials
#define WS_INTR  5242880   // f32 [64][1024]     in_tr state
#define WS_INTRT 5505024   // bf16 [1024][64]    in_tr transposed (B-operand for outer1)
#define WS_L1B   5636096   // bf16 [64][2048]    l1 spikes (A-operand for gemm2)
#define WS_L1TR  5898240   // bf16 [2][64][2048] l1_tr parity buffers
#define WS_L1TRT 6422528   // bf16 [2][2048][64] l1_tr transposed parity
#define WS_L2TRT 6946816   // bf16 [256][64]     l2_tr transposed
#define WS_BAR   6979584   // unsigned [2]: {count, generation}

typedef __attribute__((ext_vector_type(8))) short short8v;
typedef __attribute__((ext_vector_type(4))) float float4v;

__device__ inline short f2bf(float f) {
  union { float f; uint32_t u; } c; c.f = f;
  uint32_t u = c.u + 0x7fffu + ((c.u >> 16) & 1u);  // RNE
  return (short)(u >> 16);
}

// ---- hand-rolled grid barrier (sense-reversing via generation counter) ----
// __threadfence() = agent-scope fence: on gfx950 this emits the L2
// writeback/invalidate required for cross-XCD visibility of plain stores.
__device__ inline void gbar(unsigned* cnt, unsigned* gen, int tid) {
  __syncthreads();
  if (tid == 0) {
    __threadfence();  // release: make this block's writes visible
    unsigned g = __hip_atomic_load(gen, __ATOMIC_RELAXED, __HIP_MEMORY_SCOPE_AGENT);
    unsigned old = __hip_atomic_fetch_add(cnt, 1u, __ATOMIC_ACQ_REL, __HIP_MEMORY_SCOPE_AGENT);
    if (old == NBLK - 1u) {
      __hip_atomic_store(cnt, 0u, __ATOMIC_RELAXED, __HIP_MEMORY_SCOPE_AGENT);
      __hip_atomic_fetch_add(gen, 1u, __ATOMIC_RELEASE, __HIP_MEMORY_SCOPE_AGENT);
    } else {
      while (__hip_atomic_load(gen, __ATOMIC_RELAXED, __HIP_MEMORY_SCOPE_AGENT) == g) {
        __builtin_amdgcn_s_sleep(1);
      }
    }
    __threadfence();  // acquire: invalidate stale L1/L2 lines before reading
  }
  __syncthreads();
}

// ---- staging helpers (global -> LDS bf16, rows = output dim, padded stride) ----

__device__ inline void stage_f32_64x128(const float* __restrict__ src, int rowstride,
                                        short* dst, int tid) {
  for (int e = tid * 4; e < 8192; e += 1024) {
    int r = e >> 7, c = e & 127;
    float4 v = *(const float4*)(src + r * rowstride + c);
    short4 s;
    s.x = f2bf(v.x); s.y = f2bf(v.y); s.z = f2bf(v.z); s.w = f2bf(v.w);
    *(short4*)&dst[r * 136 + c] = s;
  }
}

__device__ inline void stage_bf_64x128(const short* __restrict__ src, int rowstride,
                                       short* dst, int tid) {
  for (int e = tid * 4; e < 8192; e += 1024) {
    int r = e >> 7, c = e & 127;
    *(short4*)&dst[r * 136 + c] = *(const short4*)(src + r * rowstride + c);
  }
}

__device__ inline void stage_bf_128x64(const short* __restrict__ src, short* dst, int tid) {
  for (int e = tid * 4; e < 8192; e += 1024) {
    int r = e >> 6, c = e & 63;
    *(short4*)&dst[r * 72 + c] = *(const short4*)(src + r * 64 + c);
  }
}

// ---- MFMA tile cores ----
// Operands stored [own-output-dim][k] in LDS. A rows = m, B rows = n.
// mfma_f32_16x16x32_bf16: A/B frag: lane holds row (lane&15), 8 contiguous k at
// k0=(lane>>4)*8; C/D: col=lane&15, row=(lane>>4)*4+reg.

__device__ inline void mfma_64x64_k128(const short* As, const short* Bs, int tid,
                                       float4v acc[4]) {
  int lane = tid & 63, wv = tid >> 6;
  int mr = lane & 15, q = lane >> 4;
  float4v z = {0.f, 0.f, 0.f, 0.f};
  acc[0] = z; acc[1] = z; acc[2] = z; acc[3] = z;
#pragma unroll
  for (int kf = 0; kf < 4; kf++) {
    int koff = kf * 32 + q * 8;
    short8v bf = *(const short8v*)&Bs[(wv * 16 + mr) * 136 + koff];
#pragma unroll
    for (int mt = 0; mt < 4; mt++) {
      short8v af = *(const short8v*)&As[(mt * 16 + mr) * 136 + koff];
      acc[mt] = __builtin_amdgcn_mfma_f32_16x16x32_bf16(af, bf, acc[mt], 0, 0, 0);
    }
  }
}

__device__ inline void mfma_128x128_k64(const short* As, const short* Bs, int tid,
                                        float4v acc[16]) {
  int lane = tid & 63, wv = tid >> 6;
  int mr = lane & 15, q = lane >> 4;
  float4v z = {0.f, 0.f, 0.f, 0.f};
#pragma unroll
  for (int i = 0; i < 16; i++) acc[i] = z;
#pragma unroll
  for (int kf = 0; kf < 2; kf++) {
    int koff = kf * 32 + q * 8;
    short8v bf0 = *(const short8v*)&Bs[((wv * 2 + 0) * 16 + mr) * 72 + koff];
    short8v bf1 = *(const short8v*)&Bs[((wv * 2 + 1) * 16 + mr) * 72 + koff];
#pragma unroll
    for (int mt = 0; mt < 8; mt++) {
      short8v af = *(const short8v*)&As[(mt * 16 + mr) * 72 + koff];
      acc[mt * 2 + 0] = __builtin_amdgcn_mfma_f32_16x16x32_bf16(af, bf0, acc[mt * 2 + 0], 0, 0, 0);
      acc[mt * 2 + 1] = __builtin_amdgcn_mfma_f32_16x16x32_bf16(af, bf1, acc[mt * 2 + 1], 0, 0, 0);
    }
  }
}

// ---- phase A: gemm1 split-K partials (0-255) + in_tr update (256-271)
//      + deferred LIF2(t-1) (272-279) ----
__device__ void phaseA(const float* __restrict__ x, const float* __restrict__ w_in,
                       float* __restrict__ out, char* __restrict__ ws, int t,
                       int bid, int tid, short* lds) {
  if (bid < 256) {
    int ht = bid >> 3, kc = bid & 7;
    int h0 = ht * 64, k0 = kc * 128;
    stage_f32_64x128(x + t * INN + k0, TT * INN, lds, tid);
    stage_f32_64x128(w_in + h0 * INN + k0, INN, lds + 64 * 136, tid);
    __syncthreads();
    float4v acc[4];
    mfma_64x64_k128(lds, lds + 64 * 136, tid, acc);
    float* pc1 = (float*)(ws + WS_PC1);
    int lane = tid & 63, wv = tid >> 6, mr = lane & 15, q = lane >> 4;
#pragma unroll
    for (int mt = 0; mt < 4; mt++)
#pragma unroll
      for (int r = 0; r < 4; r++) {
        int b = mt * 16 + q * 4 + r;
        pc1[(kc * 64 + b) * HIDD + h0 + wv * 16 + mr] = acc[mt][r];
      }
  } else if (bid < 272) {
    float* intr = (float*)(ws + WS_INTR);
    short* intrT = (short*)(ws + WS_INTRT);
    int g = (bid - 256) * 256 + tid;
    for (int e = g; e < BB * INN; e += 4096) {
      int b = e >> 10, i = e & 1023;
      float xv = x[(b * TT + t) * INN + i];
      float nv = DECAYF * intr[e] + (1.0f - DECAYF) * xv;
      intr[e] = nv;
      intrT[i * 64 + b] = f2bf(nv);
    }
  } else if (t > 0) {
    float* pc2 = (float*)(ws + WS_PC2);
    short* l2trT = (short*)(ws + WS_L2TRT);
    int g = (bid - 272) * 256 + tid;
    for (int e = g; e < BB * OUTT; e += 2048) {
      int b = e >> 8, o = e & 255;
      float s = 0.f;
#pragma unroll
      for (int kk = 0; kk < 16; kk++) s += pc2[(kk * 64 + b) * OUTT + o];
      float v = ALPHAF * out[O_V2 + e] + SCLF * s;
      float z = v > 1.0f ? 1.0f : 0.0f;
      v -= z;
      out[O_V2 + e] = v;
      out[O_L2SEQ + (b * TT + (t - 1)) * OUTT + o] = z;
      float tr = DECAYF * out[O_L2TR + e] + (1.0f - DECAYF) * z;
      out[O_L2TR + e] = tr;
      l2trT[o * 64 + b] = f2bf(tr);
    }
  }
}

// ---- phase B: LIF1(t) (0-63) + outer2/w_hid update for t-1 (64-95) ----
__device__ void phaseB(float* __restrict__ out, char* __restrict__ ws,
                       float* __restrict__ w_hid, int t, int bid, int tid, short* lds) {
  if (bid < 64) {
    float* pc1 = (float*)(ws + WS_PC1);
    short* l1b = (short*)(ws + WS_L1B);
    short* l1tr = (short*)(ws + WS_L1TR) + (t & 1) * BB * HIDD;
    short* l1trT = (short*)(ws + WS_L1TRT) + (t & 1) * BB * HIDD;
    int g = bid * 256 + tid;
    int b = g >> 8, h0 = (g & 255) * 8;
    float av[8] = {0.f, 0.f, 0.f, 0.f, 0.f, 0.f, 0.f, 0.f};
#pragma unroll
    for (int kk = 0; kk < 8; kk++) {
      const float* p = &pc1[(kk * 64 + b) * HIDD + h0];
      float4 u = *(const float4*)p;
      float4 w = *(const float4*)(p + 4);
      av[0] += u.x; av[1] += u.y; av[2] += u.z; av[3] += u.w;
      av[4] += w.x; av[5] += w.y; av[6] += w.z; av[7] += w.w;
    }
#pragma unroll
    for (int j = 0; j < 8; j++) {
      int h = h0 + j;
      int e = b * HIDD + h;
      float v = ALPHAF * out[O_V1 + e] + SCLF * av[j];
      float z = v > 1.0f ? 1.0f : 0.0f;
      v -= z;
      out[O_V1 + e] = v;
      out[O_L1SEQ + (b * TT + t) * HIDD + h] = z;
      l1b[e] = f2bf(z);
      float tr = DECAYF * out[O_L1TR + e] + (1.0f - DECAYF) * z;
      out[O_L1TR + e] = tr;
      short sb = f2bf(tr);
      l1tr[e] = sb;
      l1trT[h * 64 + b] = sb;
    }
  } else if (bid < 96 && t > 0) {
    int idx = bid - 64;
    int ob = idx >> 4, hb = idx & 15;
    int o0 = ob * 128, h0 = hb * 128;
    short* l2trT = (short*)(ws + WS_L2TRT);
    short* l1trTp = (short*)(ws + WS_L1TRT) + ((t - 1) & 1) * BB * HIDD;
    stage_bf_128x64(l2trT + o0 * 64, lds, tid);
    stage_bf_128x64(l1trTp + h0 * 64, lds + 128 * 72, tid);
    __syncthreads();
    float4v acc[16];
    mfma_128x128_k64(lds, lds + 128 * 72, tid, acc);
    int lane = tid & 63, wv = tid >> 6, mr = lane & 15, q = lane >> 4;
#pragma unroll
    for (int mt = 0; mt < 8; mt++)
#pragma unroll
      for (int n2 = 0; n2 < 2; n2++)
#pragma unroll
        for (int r = 0; r < 4; r++) {
          int o = o0 + mt * 16 + q * 4 + r;
          int h = h0 + (wv * 2 + n2) * 16 + mr;
          int e = o * HIDD + h;
          float w = w_hid[e];
          w_hid[e] = w * (1.0f - LRF * WDF) + (LRF / 64.0f) * acc[mt * 2 + n2][r];
        }
  }
}

// ---- phase C: gemm2 split-K partials (0-63) + outer1/w_in update for t (64-191) ----
__device__ void phaseC(float* __restrict__ w_in, const float* __restrict__ w_hid,
                       char* __restrict__ ws, int t, int bid, int tid, short* lds) {
  if (bid < 64) {
    int ot = bid >> 4, kc = bid & 15;
    int o0 = ot * 64, k0 = kc * 128;
    short* l1b = (short*)(ws + WS_L1B);
    stage_bf_64x128(l1b + k0, HIDD, lds, tid);
    stage_f32_64x128(w_hid + o0 * HIDD + k0, HIDD, lds + 64 * 136, tid);
    __syncthreads();
    float4v acc[4];
    mfma_64x64_k128(lds, lds + 64 * 136, tid, acc);
    float* pc2 = (float*)(ws + WS_PC2);
    int lane = tid & 63, wv = tid >> 6, mr = lane & 15, q = lane >> 4;
#pragma unroll
    for (int mt = 0; mt < 4; mt++)
#pragma unroll
      for (int r = 0; r < 4; r++) {
        int b = mt * 16 + q * 4 + r;
        pc2[(kc * 64 + b) * OUTT + o0 + wv * 16 + mr] = acc[mt][r];
      }
  } else if (bid < 192) {
    int idx = bid - 64;
    int hb = idx >> 3, ib = idx & 7;
    int h0 = hb * 128, i0 = ib * 128;
    short* l1trT = (short*)(ws + WS_L1TRT) + (t & 1) * BB * HIDD;
    short* intrT = (short*)(ws + WS_INTRT);
    stage_bf_128x64(l1trT + h0 * 64, lds, tid);
    stage_bf_128x64(intrT + i0 * 64, lds + 128 * 72, tid);
    __syncthreads();
    float4v acc[16];
    mfma_128x128_k64(lds, lds + 128 * 72, tid, acc);
    int lane = tid & 63, wv = tid >> 6, mr = lane & 15, q = lane >> 4;
#pragma unroll
    for (int mt = 0; mt < 8; mt++)
#pragma unroll
      for (int n2 = 0; n2 < 2; n2++)
#pragma unroll
        for (int r = 0; r < 4; r++) {
          int h = h0 + mt * 16 + q * 4 + r;
          int i = i0 + (wv * 2 + n2) * 16 + mr;
          int e = h * INN + i;
          float w = w_in[e];
          w_in[e] = w * (1.0f - LRF * WDF) + (LRF / 64.0f) * acc[mt * 2 + n2][r];
        }
  }
}

// ---- init kernel (regular launch): zero state + barrier counters.
//      The kernel boundary between k_init and k_persist is the init sync. ----
__global__ __launch_bounds__(256) void k_init(float* __restrict__ out, char* __restrict__ ws) {
  int g = blockIdx.x * blockDim.x + threadIdx.x;
  int n = gridDim.x * blockDim.x;
  for (int e = g; e < BB * HIDD; e += n) { out[O_V1 + e] = 0.f; out[O_L1TR + e] = 0.f; }
  for (int e = g; e < BB * OUTT; e += n) { out[O_V2 + e] = 0.f; out[O_L2TR + e] = 0.f; }
  float* intr = (float*)(ws + WS_INTR);
  for (int e = g; e < BB * INN; e += n) intr[e] = 0.f;
  if (g < 2) ((unsigned*)(ws + WS_BAR))[g] = 0u;
}

// ---- the single persistent kernel (regular launch + hand-rolled grid barrier) ----
// __launch_bounds__(256,2): guarantee >=2 blocks/CU => capacity 512 >= 280 blocks,
// so all blocks are co-resident and the barrier cannot deadlock.
__global__ __launch_bounds__(256, 2) void k_persist(const float* __restrict__ x,
                                                    float* __restrict__ w_in,
                                                    float* __restrict__ w_hid,
                                                    float* __restrict__ out,
                                                    char* __restrict__ ws) {
  __shared__ short lds[2 * 128 * 72];
  int bid = blockIdx.x, tid = threadIdx.x;
  unsigned* bar_cnt = (unsigned*)(ws + WS_BAR);
  unsigned* bar_gen = bar_cnt + 1;

  for (int t = 0; t < TT; t++) {
    phaseA(x, w_in, out, ws, t, bid, tid, lds);
    gbar(bar_cnt, bar_gen, tid);
    phaseB(out, ws, w_hid, t, bid, tid, lds);
    gbar(bar_cnt, bar_gen, tid);
    phaseC(w_in, w_hid, ws, t, bid, tid, lds);
    gbar(bar_cnt, bar_gen, tid);
  }

  // epilogue: LIF2 for final step (t-1 = 249), distributed over the whole grid
  {
    float* pc2 = (float*)(ws + WS_PC2);
    int g = bid * 256 + tid;
    int n = (int)NBLK * 256;
    for (int e = g; e < BB * OUTT; e += n) {
      int b = e >> 8, o = e & 255;
      float s = 0.f;
#pragma unroll
      for (int kk = 0; kk < 16; kk++) s += pc2[(kk * 64 + b) * OUTT + o];
      float v = ALPHAF * out[O_V2 + e] + SCLF * s;
      float z = v > 1.0f ? 1.0f : 0.0f;
      v -= z;
      out[O_V2 + e] = v;
      out[O_L2SEQ + (b * TT + (TT - 1)) * OUTT + o] = z;
      float tr = DECAYF * out[O_L2TR + e] + (1.0f - DECAYF) * z;
      out[O_L2TR + e] = tr;
    }
  }
}

extern "C" void kernel_launch(void* const* d_in, const int* in_sizes, int n_in,
                              void* d_out, int out_size, void* d_ws, size_t ws_size,
                              hipStream_t stream) {
  const float* x = (const float*)d_in[0];
  float* w_in = (float*)d_in[1];    // mutated in place; harness restores each launch
  float* w_hid = (float*)d_in[2];
  float* out = (float*)d_out;
  char* ws = (char*)d_ws;

  hipLaunchKernelGGL(k_init, dim3(256), dim3(256), 0, stream, out, ws);
  hipLaunchKernelGGL(k_persist, dim3(NBLK), dim3(256), 0, stream, x, w_in, w_hid, out, ws);
}

// Round 4
// 9063.583 us; speedup vs baseline: 4.9276x; 4.9276x over previous
//
#include <hip/hip_runtime.h>
#include <stdint.h>

// Problem constants
#define BB   64
#define TT   250
#define INN  1024
#define HIDD 2048
#define OUTT 256

#define DECAYF 0.951229424500714f   // exp(-1/20)
#define ALPHAF 0.951229424500714f
#define LRF    1e-4f
#define WDF    0.01f
#define SCLF   0.2f

// block roles
#define N_L1   128               // w_in tiles [16h x 1024], LDS-resident bf16
#define N_L2   16                // w_hid rows [16o x 2048], global f32 (block-private)
#define N_HELP 8                 // x->bf16 + in_tr state + in_trT producer
#define NBLK   152u

// d_out offsets (float elements), return order:
// l1_seq [64,250,2048], l2_seq [64,250,256], v1, v2, l1_tr, l2_tr
#define O_L1SEQ 0
#define O_L2SEQ 32768000
#define O_V1    36864000
#define O_V2    36995072
#define O_L1TR  37011456
#define O_L2TR  37142528

// workspace (byte offsets); all parity double-buffered by step
#define WS_XBF   0u         // bf16 [2][64][1024]   x_t as bf16 (gemm1 A)
#define WS_INTRT 262144u    // bf16 [2][1024][64]   in_tr^T (outer1 B)
#define WS_L1B   524288u    // bf16 [2][64][2048]   l1 spikes (gemm2 A)
#define WS_L1TRT 1048576u   // bf16 [2][2048][64]   l1_tr^T (outer2 B)
#define WS_INTR  1572864u   // f32 [64][1024]       in_tr state (helper-private)
#define WS_BAR   1835008u   // u32[2]: {count, generation}

typedef __attribute__((ext_vector_type(8))) short short8v;
typedef __attribute__((ext_vector_type(4))) float float4v;

__device__ inline short f2bf(float f) {
  union { float f; uint32_t u; } c; c.f = f;
  uint32_t u = c.u + 0x7fffu + ((c.u >> 16) & 1u);  // RNE
  return (short)(u >> 16);
}
__device__ inline float bf2f(short s) {
  union { uint32_t u; float f; } c; c.u = ((uint32_t)(uint16_t)s) << 16;
  return c.f;
}

// ---- grid barrier (R3-proven semantics; fewer blocks, slower poll) ----
__device__ inline void gbar(unsigned* cnt, unsigned* gen, int tid) {
  __syncthreads();
  if (tid == 0) {
    __threadfence();  // release: L2 writeback (dirty set is now tiny)
    unsigned g = __hip_atomic_load(gen, __ATOMIC_RELAXED, __HIP_MEMORY_SCOPE_AGENT);
    unsigned old = __hip_atomic_fetch_add(cnt, 1u, __ATOMIC_ACQ_REL, __HIP_MEMORY_SCOPE_AGENT);
    if (old == NBLK - 1u) {
      __hip_atomic_store(cnt, 0u, __ATOMIC_RELAXED, __HIP_MEMORY_SCOPE_AGENT);
      __hip_atomic_fetch_add(gen, 1u, __ATOMIC_RELEASE, __HIP_MEMORY_SCOPE_AGENT);
    } else {
      while (__hip_atomic_load(gen, __ATOMIC_RELAXED, __HIP_MEMORY_SCOPE_AGENT) == g) {
        __builtin_amdgcn_s_sleep(16);
      }
    }
    __threadfence();  // acquire: invalidate stale lines
  }
  __syncthreads();
}

// MFMA layout (verified m89): D=A*B^T-ish: A[m][k] lane row=lane&15, k0=(lane>>4)*8;
// B[n][k] same; C/D: col(n)=lane&15, row(m)=(lane>>4)*4+reg.

// ================= layer-1 block: bid in [0,128), h-tile = bid*16 =================
// LDS: w bf16 [16][1032] @0 (33024 B); stg @33024 (18432 B); scr f32 [16][68] @51456 (4352 B)
__device__ void l1_work(int t, int bid, int tid, float* __restrict__ out,
                        char* __restrict__ ws, short* w, short* stg, float* scr,
                        float4v& v1, float4v& tr1) {
  const int h0 = bid * 16;
  const int wv = tid >> 6, lane = tid & 63;
  const int col = lane & 15, q = lane >> 4;
  const short* xbf = (const short*)(ws + WS_XBF) + (t & 1) * (BB * INN);

  // ---- gemm1: cur1[64b x 16h], K=1024 in 8 chunks of 128
  float4v acc = {0.f, 0.f, 0.f, 0.f};
  for (int kc = 0; kc < 8; ++kc) {
    for (int rnd = 0; rnd < 4; ++rnd) {
      int idx = rnd * 2048 + tid * 8;
      int r = idx >> 7, c = idx & 127;
      *(short8v*)&stg[r * 136 + c] = *(const short8v*)&xbf[r * INN + kc * 128 + c];
    }
    __syncthreads();
#pragma unroll
    for (int kk = 0; kk < 4; ++kk) {
      short8v af = *(const short8v*)&stg[(wv * 16 + col) * 136 + kk * 32 + q * 8];
      short8v bf = *(const short8v*)&w[col * 1032 + kc * 128 + kk * 32 + q * 8];
      acc = __builtin_amdgcn_mfma_f32_16x16x32_bf16(af, bf, acc, 0, 0, 0);
    }
    __syncthreads();
  }

  // ---- LIF1 (v1, tr1 persistent in regs; element = (b=wv*16+q*4+r, h=h0+col))
  float4v zv;
#pragma unroll
  for (int r = 0; r < 4; ++r) {
    float v = ALPHAF * v1[r] + SCLF * acc[r];
    float z = v > 1.0f ? 1.0f : 0.0f;
    v -= z;
    v1[r] = v;
    zv[r] = z;
    tr1[r] = DECAYF * tr1[r] + (1.0f - DECAYF) * z;
  }
  short* l1b = (short*)(ws + WS_L1B) + (t & 1) * (BB * HIDD);
  short* l1trT = (short*)(ws + WS_L1TRT) + (t & 1) * (HIDD * BB);
#pragma unroll
  for (int r = 0; r < 4; ++r) {
    int b = wv * 16 + q * 4 + r;
    out[O_L1SEQ + (b * TT + t) * HIDD + h0 + col] = zv[r];
    l1b[b * HIDD + h0 + col] = f2bf(zv[r]);
    scr[col * 68 + b] = tr1[r];
    if (t == TT - 1) {
      out[O_V1 + b * HIDD + h0 + col] = v1[r];
      out[O_L1TR + b * HIDD + h0 + col] = tr1[r];
    }
  }
  __syncthreads();
  // publish l1_tr^T rows (16 h x 64 b)
  {
    int idx = tid * 4;
    int hl = idx >> 6, b = idx & 63;
    short4 s4;
    s4.x = f2bf(scr[hl * 68 + b + 0]);
    s4.y = f2bf(scr[hl * 68 + b + 1]);
    s4.z = f2bf(scr[hl * 68 + b + 2]);
    s4.w = f2bf(scr[hl * 68 + b + 3]);
    *(short4*)&l1trT[(h0 + hl) * 64 + b] = s4;
  }

  // ---- w_in update: w = w*(1-LR*WD) + (LR/64)*outer; outer[h][i]=sum_b tr1T[h][b]*intrT[i][b]
  const short* intrT = (const short*)(ws + WS_INTRT) + (t & 1) * (INN * BB);
  short8v afu[2];
#pragma unroll
  for (int kk = 0; kk < 2; ++kk) {
    short8v a;
#pragma unroll
    for (int j = 0; j < 8; ++j) a[j] = f2bf(scr[col * 68 + kk * 32 + q * 8 + j]);
    afu[kk] = a;
  }
  const float c0 = 1.0f - LRF * WDF, c1 = LRF / 64.0f;
  for (int ci = 0; ci < 8; ++ci) {
    __syncthreads();
    for (int rnd = 0; rnd < 4; ++rnd) {
      int idx = rnd * 2048 + tid * 8;
      int r = idx >> 6, c = idx & 63;
      *(short8v*)&stg[r * 72 + c] = *(const short8v*)&intrT[(ci * 128 + r) * 64 + c];
    }
    __syncthreads();
#pragma unroll
    for (int j = 0; j < 2; ++j) {
      int nt = wv * 2 + j;
      float4v au = {0.f, 0.f, 0.f, 0.f};
#pragma unroll
      for (int kk = 0; kk < 2; ++kk) {
        short8v bf = *(const short8v*)&stg[(nt * 16 + col) * 72 + kk * 32 + q * 8];
        au = __builtin_amdgcn_mfma_f32_16x16x32_bf16(afu[kk], bf, au, 0, 0, 0);
      }
#pragma unroll
      for (int r = 0; r < 4; ++r) {
        int hrow = q * 4 + r;
        int icol = ci * 128 + nt * 16 + col;
        float oldw = bf2f(w[hrow * 1032 + icol]);
        w[hrow * 1032 + icol] = f2bf(oldw * c0 + c1 * au[r]);
      }
    }
  }
}

// ================= layer-2 block: bid-128 in [0,16), o-tile = idx*16 =================
// LDS: wstg bf16 [16][136] @0 (4352 B); stg @4352 (18432 B); scr f32 @22784 (4352 B)
__device__ void l2_work(int tp, int idx16, int tid, float* __restrict__ out,
                        char* __restrict__ ws, float* __restrict__ w_hid,
                        short* wstg, short* stg, float* scr,
                        float4v& v2, float4v& tr2) {
  const int o0 = idx16 * 16;
  const int wv = tid >> 6, lane = tid & 63;
  const int col = lane & 15, q = lane >> 4;
  const short* l1b = (const short*)(ws + WS_L1B) + (tp & 1) * (BB * HIDD);

  // ---- gemm2: cur2[64b x 16o], K=2048 in 16 chunks of 128
  float4v acc = {0.f, 0.f, 0.f, 0.f};
  for (int kc = 0; kc < 16; ++kc) {
    for (int rnd = 0; rnd < 4; ++rnd) {
      int idx = rnd * 2048 + tid * 8;
      int r = idx >> 7, c = idx & 127;
      *(short8v*)&stg[r * 136 + c] = *(const short8v*)&l1b[r * HIDD + kc * 128 + c];
    }
    {
      int idx = tid * 8;  // 16x128 = 2048 f32 -> bf16
      int r = idx >> 7, c = idx & 127;
      const float* src = &w_hid[(o0 + r) * HIDD + kc * 128 + c];
      float4 u = *(const float4*)src;
      float4 u2 = *(const float4*)(src + 4);
      short8v s;
      s[0] = f2bf(u.x);  s[1] = f2bf(u.y);  s[2] = f2bf(u.z);  s[3] = f2bf(u.w);
      s[4] = f2bf(u2.x); s[5] = f2bf(u2.y); s[6] = f2bf(u2.z); s[7] = f2bf(u2.w);
      *(short8v*)&wstg[r * 136 + c] = s;
    }
    __syncthreads();
#pragma unroll
    for (int kk = 0; kk < 4; ++kk) {
      short8v af = *(const short8v*)&stg[(wv * 16 + col) * 136 + kk * 32 + q * 8];
      short8v bf = *(const short8v*)&wstg[col * 136 + kk * 32 + q * 8];
      acc = __builtin_amdgcn_mfma_f32_16x16x32_bf16(af, bf, acc, 0, 0, 0);
    }
    __syncthreads();
  }

  // ---- LIF2
  float4v zv;
#pragma unroll
  for (int r = 0; r < 4; ++r) {
    float v = ALPHAF * v2[r] + SCLF * acc[r];
    float z = v > 1.0f ? 1.0f : 0.0f;
    v -= z;
    v2[r] = v;
    zv[r] = z;
    tr2[r] = DECAYF * tr2[r] + (1.0f - DECAYF) * z;
  }
#pragma unroll
  for (int r = 0; r < 4; ++r) {
    int b = wv * 16 + q * 4 + r;
    out[O_L2SEQ + (b * TT + tp) * OUTT + o0 + col] = zv[r];
    scr[col * 68 + b] = tr2[r];
    if (tp == TT - 1) {
      out[O_V2 + b * OUTT + o0 + col] = v2[r];
      out[O_L2TR + b * OUTT + o0 + col] = tr2[r];
    }
  }
  __syncthreads();

  // ---- w_hid update (global f32, block-private rows): outer[o][h]=sum_b tr2T[o][b]*l1trT[h][b]
  const short* l1trT = (const short*)(ws + WS_L1TRT) + (tp & 1) * (HIDD * BB);
  short8v afu[2];
#pragma unroll
  for (int kk = 0; kk < 2; ++kk) {
    short8v a;
#pragma unroll
    for (int j = 0; j < 8; ++j) a[j] = f2bf(scr[col * 68 + kk * 32 + q * 8 + j]);
    afu[kk] = a;
  }
  const float c0 = 1.0f - LRF * WDF, c1 = LRF / 64.0f;
  for (int ci = 0; ci < 16; ++ci) {
    __syncthreads();
    for (int rnd = 0; rnd < 4; ++rnd) {
      int idx = rnd * 2048 + tid * 8;
      int r = idx >> 6, c = idx & 63;
      *(short8v*)&stg[r * 72 + c] = *(const short8v*)&l1trT[(ci * 128 + r) * 64 + c];
    }
    __syncthreads();
#pragma unroll
    for (int j = 0; j < 2; ++j) {
      int nt = wv * 2 + j;
      float4v au = {0.f, 0.f, 0.f, 0.f};
#pragma unroll
      for (int kk = 0; kk < 2; ++kk) {
        short8v bf = *(const short8v*)&stg[(nt * 16 + col) * 72 + kk * 32 + q * 8];
        au = __builtin_amdgcn_mfma_f32_16x16x32_bf16(afu[kk], bf, au, 0, 0, 0);
      }
#pragma unroll
      for (int r = 0; r < 4; ++r) {
        int orow = o0 + q * 4 + r;
        int hcol = ci * 128 + nt * 16 + col;
        float* p = &w_hid[orow * HIDD + hcol];
        *p = *p * c0 + c1 * au[r];
      }
    }
  }
}

// ================= helper block: produce xbf(tt), in_tr(tt), in_trT(tt) =================
// LDS: trbuf f32 [64][132] @0 (33792 B)
__device__ void helper_work(int tt, int hidx, int tid, const float* __restrict__ x,
                            char* __restrict__ ws, float* trbuf) {
  const int i0 = hidx * 128;
  float* intr = (float*)(ws + WS_INTR);
  short* xbf = (short*)(ws + WS_XBF) + (tt & 1) * (BB * INN);
  short* intrT = (short*)(ws + WS_INTRT) + (tt & 1) * (INN * BB);
  for (int rnd = 0; rnd < 4; ++rnd) {
    int idx = rnd * 2048 + tid * 8;
    int b = idx >> 7, c = idx & 127;
    const float* xs = &x[(b * TT + tt) * INN + i0 + c];
    float4 xa = *(const float4*)xs, xb = *(const float4*)(xs + 4);
    float xv[8] = {xa.x, xa.y, xa.z, xa.w, xb.x, xb.y, xb.z, xb.w};
    float* ip = &intr[b * INN + i0 + c];
    float pv[8];
    if (tt == 0) {
#pragma unroll
      for (int j = 0; j < 8; ++j) pv[j] = 0.f;
    } else {
      float4 p1 = *(const float4*)ip, p2 = *(const float4*)(ip + 4);
      pv[0] = p1.x; pv[1] = p1.y; pv[2] = p1.z; pv[3] = p1.w;
      pv[4] = p2.x; pv[5] = p2.y; pv[6] = p2.z; pv[7] = p2.w;
    }
    float nv[8];
    short8v xsv;
#pragma unroll
    for (int j = 0; j < 8; ++j) {
      nv[j] = DECAYF * pv[j] + (1.0f - DECAYF) * xv[j];
      xsv[j] = f2bf(xv[j]);   // exact (0/1 spikes)
    }
    float4 n1 = {nv[0], nv[1], nv[2], nv[3]}, n2 = {nv[4], nv[5], nv[6], nv[7]};
    *(float4*)ip = n1;
    *(float4*)(ip + 4) = n2;
    *(short8v*)&xbf[b * INN + i0 + c] = xsv;
    *(float4*)&trbuf[b * 132 + c] = n1;
    *(float4*)&trbuf[b * 132 + c + 4] = n2;
  }
  __syncthreads();
  for (int rnd = 0; rnd < 4; ++rnd) {
    int idx = rnd * 2048 + tid * 8;
    int il = idx >> 6, b = idx & 63;
    short8v s;
#pragma unroll
    for (int j = 0; j < 8; ++j) s[j] = f2bf(trbuf[(b + j) * 132 + il]);
    *(short8v*)&intrT[(i0 + il) * 64 + b] = s;
  }
  __syncthreads();
}

// ---- init: zero barrier state (ws is poisoned 0xAA each launch) ----
__global__ __launch_bounds__(64) void k_init(char* __restrict__ ws) {
  if (threadIdx.x < 2) ((unsigned*)(ws + WS_BAR))[threadIdx.x] = 0u;
}

__global__ __launch_bounds__(256) void k_persist(const float* __restrict__ x,
                                                 const float* __restrict__ w_in,
                                                 float* __restrict__ w_hid,
                                                 float* __restrict__ out,
                                                 char* __restrict__ ws) {
  __shared__ __align__(16) char smem[55808];
  const int bid = blockIdx.x, tid = threadIdx.x;
  unsigned* bar = (unsigned*)(ws + WS_BAR);
  float4v vst = {0.f, 0.f, 0.f, 0.f};   // v1 (L1 blocks) / v2 (L2 blocks)
  float4v trs = {0.f, 0.f, 0.f, 0.f};   // l1_tr / l2_tr

  // ---- prologue
  if (bid < N_L1) {
    // load w_in tile [16h x 1024] f32 -> bf16 LDS (the only global read of w_in, ever)
    short* w = (short*)smem;
    int r = tid >> 4, c0 = (tid & 15) * 64;
    for (int cc = 0; cc < 64; cc += 4) {
      float4 u = *(const float4*)&w_in[(bid * 16 + r) * INN + c0 + cc];
      short4 s;
      s.x = f2bf(u.x); s.y = f2bf(u.y); s.z = f2bf(u.z); s.w = f2bf(u.w);
      *(short4*)&w[r * 1032 + c0 + cc] = s;
    }
  } else if (bid >= N_L1 + N_L2) {
    helper_work(0, bid - (N_L1 + N_L2), tid, x, ws, (float*)smem);
  }
  gbar(bar, bar + 1, tid);

  // ---- supersteps: L1 does step t, L2 does step t-1, helpers prepare t+1
  for (int t = 0; t <= TT; ++t) {
    if (bid < N_L1) {
      if (t < TT)
        l1_work(t, bid, tid, out, ws, (short*)smem, (short*)(smem + 33024),
                (float*)(smem + 51456), vst, trs);
    } else if (bid < N_L1 + N_L2) {
      if (t >= 1)
        l2_work(t - 1, bid - N_L1, tid, out, ws, w_hid, (short*)smem,
                (short*)(smem + 4352), (float*)(smem + 22784), vst, trs);
    } else {
      if (t + 1 < TT)
        helper_work(t + 1, bid - (N_L1 + N_L2), tid, x, ws, (float*)smem);
    }
    if (t < TT) gbar(bar, bar + 1, tid);
  }
}

extern "C" void kernel_launch(void* const* d_in, const int* in_sizes, int n_in,
                              void* d_out, int out_size, void* d_ws, size_t ws_size,
                              hipStream_t stream) {
  const float* x = (const float*)d_in[0];
  const float* w_in = (const float*)d_in[1];
  float* w_hid = (float*)d_in[2];   // mutated in place; harness restores each launch
  float* out = (float*)d_out;
  char* ws = (char*)d_ws;

  hipLaunchKernelGGL(k_init, dim3(1), dim3(64), 0, stream, ws);
  hipLaunchKernelGGL(k_persist, dim3(NBLK), dim3(256), 0, stream, x, w_in, w_hid, out, ws);
}